// Round 10
// baseline (211.068 us; speedup 1.0000x reference)
//
#include <hip/hip_runtime.h>
#include <hip/hip_bf16.h>
#include <math.h>

#define B_ 8
#define C_ 512
#define N_ 2048
#define D_ 64
#define O_ 640   // 64 + 64 + 512

typedef __bf16 bf16x8 __attribute__((ext_vector_type(8)));
typedef float f32x4 __attribute__((ext_vector_type(4)));
typedef unsigned short ushort8_t __attribute__((ext_vector_type(8)));
typedef unsigned short ushort4_t __attribute__((ext_vector_type(4)));

__device__ __forceinline__ unsigned short f2bf(float f) {
    unsigned int u = __builtin_bit_cast(unsigned int, f);
    u += 0x7fffu + ((u >> 16) & 1u);
    return (unsigned short)(u >> 16);
}

__device__ __forceinline__ float fastexp(float x) {
    return exp2f(x * 1.44269504088896340736f);
}

union FragU { ushort8_t u; bf16x8 b; };

__device__ __forceinline__ bf16x8 ldfrag(const unsigned short* p) {
    FragU t; t.u = *(const ushort8_t*)p; return t.b;
}

__device__ __forceinline__ void gload_lds16(const unsigned short* g, unsigned short* l) {
    __builtin_amdgcn_global_load_lds((const __attribute__((address_space(1))) void*)g,
                                     (__attribute__((address_space(3))) void*)l,
                                     16, 0, 0);
}

// ================= sigma chain: scale[which] = ||t|| / ||W t||, t = W^T u =================
__global__ __launch_bounds__(512) void k_colvec(const float* __restrict__ Wq,
                                                const float* __restrict__ Wk,
                                                const float* __restrict__ Wv,
                                                const float* __restrict__ uq,
                                                const float* __restrict__ uk,
                                                const float* __restrict__ uv,
                                                float* __restrict__ tpart) {
    int which = blockIdx.y, oq = blockIdx.x;
    const float* W; const float* u; int R;
    if (which == 0)      { W = Wq; u = uq; R = 64;  }
    else if (which == 1) { W = Wk; u = uk; R = 64;  }
    else                 { W = Wv; u = uv; R = 512; }
    int chunk = R >> 2;
    int i = threadIdx.x;
    float s = 0.f;
    int o0 = oq * chunk, o1 = o0 + chunk;
    for (int o = o0; o < o1; ++o) s += W[(size_t)o * 512 + i] * u[o];
    tpart[((which << 2) + oq) * 512 + i] = s;
}

__global__ __launch_bounds__(512) void k_trow(const float* __restrict__ tpart,
                                              float* __restrict__ tvec,
                                              float* __restrict__ t2) {
    int which = blockIdx.x, i = threadIdx.x;
    const float* tp = tpart + (which << 2) * 512;
    float s = tp[i] + tp[512 + i] + tp[1024 + i] + tp[1536 + i];
    tvec[which * 512 + i] = s;
    __shared__ float red[512];
    red[i] = s * s; __syncthreads();
    for (int st = 256; st > 0; st >>= 1) { if (i < st) red[i] += red[i + st]; __syncthreads(); }
    if (i == 0) t2[which] = red[0];
}

__global__ __launch_bounds__(256) void k_rowvec(const float* __restrict__ Wq,
                                                const float* __restrict__ Wk,
                                                const float* __restrict__ Wv,
                                                const float* __restrict__ tvec,
                                                float* __restrict__ wpart) {
    int which = blockIdx.y;
    const float* W; int R;
    if (which == 0)      { W = Wq; R = 64;  }
    else if (which == 1) { W = Wk; R = 64;  }
    else                 { W = Wv; R = 512; }
    int tid = threadIdx.x, lane = tid & 63, wv = tid >> 6;
    int row = blockIdx.x * 4 + wv;
    float ps = 0.f;
    if (row < R) {
        const float4* wr_ = (const float4*)(W + (size_t)row * 512);
        const float4* tv = (const float4*)(tvec + which * 512);
        float4 a0 = wr_[lane * 2], a1 = wr_[lane * 2 + 1];
        float4 b0 = tv[lane * 2], b1 = tv[lane * 2 + 1];
        float s = a0.x * b0.x + a0.y * b0.y + a0.z * b0.z + a0.w * b0.w
                + a1.x * b1.x + a1.y * b1.y + a1.z * b1.z + a1.w * b1.w;
        #pragma unroll
        for (int off = 1; off < 64; off <<= 1) s += __shfl_xor(s, off, 64);
        ps = s * s;
    }
    __shared__ float red[4];
    if (lane == 0) red[wv] = ps;
    __syncthreads();
    if (tid == 0) wpart[which * 128 + blockIdx.x] = red[0] + red[1] + red[2] + red[3];
}

__global__ __launch_bounds__(128) void k_scale(const float* __restrict__ wpart,
                                               const float* __restrict__ t2,
                                               float* __restrict__ scales) {
    int which = blockIdx.x, tid = threadIdx.x;
    float s = wpart[which * 128 + tid];
    #pragma unroll
    for (int off = 1; off < 64; off <<= 1) s += __shfl_xor(s, off, 64);
    __shared__ float r2[2];
    if ((tid & 63) == 0) r2[tid >> 6] = s;
    __syncthreads();
    if (tid == 0) scales[which] = sqrtf(t2[which] / fmaxf(r2[0] + r2[1], 1e-24f));
}

// ---------------- wconv: Wb[o][i] = bf16(W[o][i] * scale) ----------------
__global__ __launch_bounds__(256) void k_wconv(const float* __restrict__ Wq,
                                               const float* __restrict__ Wk,
                                               const float* __restrict__ Wv,
                                               const float* __restrict__ scales,
                                               unsigned short* __restrict__ Wb) {
    int gid = blockIdx.x * 256 + threadIdx.x;
    int e0 = gid * 8;
    int o = e0 >> 9, i = e0 & 511;
    const float* src; float sc;
    if (o < 64)       { src = Wq + (size_t)o * 512;         sc = scales[0]; }
    else if (o < 128) { src = Wk + (size_t)(o - 64) * 512;  sc = scales[1]; }
    else              { src = Wv + (size_t)(o - 128) * 512; sc = scales[2]; }
    float4 v0 = *(const float4*)(src + i), v1 = *(const float4*)(src + i + 4);
    ushort8_t u;
    u[0] = f2bf(v0.x * sc); u[1] = f2bf(v0.y * sc); u[2] = f2bf(v0.z * sc); u[3] = f2bf(v0.w * sc);
    u[4] = f2bf(v1.x * sc); u[5] = f2bf(v1.y * sc); u[6] = f2bf(v1.z * sc); u[7] = f2bf(v1.w * sc);
    *(ushort8_t*)&Wb[(size_t)o * 512 + i] = u;
}

// ---------------- transpose: x [B,C,N] f32 -> xT [B,N,C] bf16 ----------------
__global__ __launch_bounds__(256) void k_transpose(const float* __restrict__ x,
                                                   unsigned short* __restrict__ xT) {
    __shared__ float tile[64][33];   // [c][n]
    int b = blockIdx.z;
    int n0 = blockIdx.x * 32, c0 = blockIdx.y * 64;
    int tx = threadIdx.x, ty = threadIdx.y;  // tx: 0..31 (n), ty: 0..7
    #pragma unroll
    for (int k = 0; k < 8; ++k) {
        int c = ty + k * 8;
        tile[c][tx] = x[((size_t)b * C_ + c0 + c) * N_ + n0 + tx];
    }
    __syncthreads();
    #pragma unroll
    for (int k = 0; k < 4; ++k) {
        int n = ty + k * 8;
        unsigned int p = (unsigned int)f2bf(tile[tx * 2][n]) |
                         ((unsigned int)f2bf(tile[tx * 2 + 1][n]) << 16);
        *(unsigned int*)&xT[((size_t)b * N_ + n0 + n) * C_ + c0 + tx * 2] = p;
    }
}

// ---------------- proj (pipelined): D[n,o] = sum_i xT[n,i] * Wb[o,i]; 128x128, BK=64 ----------------
// Double-buffered (64 KB LDS): STAGE(kt+1) issued BEFORE compute(kt); one vmcnt(0)+barrier per tile.
__global__ __launch_bounds__(256) void k_proj(const unsigned short* __restrict__ xT,
                                              const unsigned short* __restrict__ Wb,
                                              unsigned short* __restrict__ fT,
                                              unsigned short* __restrict__ gT,
                                              unsigned short* __restrict__ hb) {
    const int NT = 8;
    int b = blockIdx.z, n0 = blockIdx.y * 128, o0 = blockIdx.x * 128;
    int tid = threadIdx.x, lane = tid & 63, w = tid >> 6;
    int wr = w >> 1, wc = w & 1;
    __shared__ __align__(16) unsigned short Sh[32768];   // 64 KB: A0 A1 B0 B1 (8K u16 each)
    f32x4 zero = {0.f, 0.f, 0.f, 0.f};
    f32x4 acc[4][4];
    #pragma unroll
    for (int i = 0; i < 4; ++i)
        #pragma unroll
        for (int j = 0; j < 4; ++j) acc[i][j] = zero;
    int r8 = lane >> 3, sl = lane & 7;
    int scol = (sl ^ r8) * 8;   // pre-swizzled source column (elements)

    auto STAGE = [&](int kt, int p) {
        unsigned short* As = Sh + p * 8192;
        unsigned short* Bs = Sh + 16384 + p * 8192;
        #pragma unroll
        for (int q = 0; q < 4; ++q) {
            int chunk = w * 4 + q;
            int row = chunk * 8 + r8;
            gload_lds16(xT + ((size_t)b * N_ + n0 + row) * C_ + kt * 64 + scol, &As[chunk * 512]);
            gload_lds16(Wb + (size_t)(o0 + row) * C_ + kt * 64 + scol, &Bs[chunk * 512]);
        }
    };

    STAGE(0, 0);
    asm volatile("s_waitcnt vmcnt(0)" ::: "memory");
    __builtin_amdgcn_sched_barrier(0);
    __builtin_amdgcn_s_barrier();
    __builtin_amdgcn_sched_barrier(0);

    int kg = lane >> 4, r16 = lane & 15;
    #pragma unroll 1
    for (int kt = 0; kt < NT; ++kt) {
        int p = kt & 1;
        if (kt + 1 < NT) STAGE(kt + 1, p ^ 1);
        __builtin_amdgcn_sched_barrier(0);
        const unsigned short* As = Sh + p * 8192;
        const unsigned short* Bs = Sh + 16384 + p * 8192;
        __builtin_amdgcn_s_setprio(1);
        #pragma unroll
        for (int kk = 0; kk < 2; ++kk) {
            int sw = kk * 4 + kg;
            bf16x8 af[4];
            #pragma unroll
            for (int i = 0; i < 4; ++i) {
                int row = wr * 64 + i * 16 + r16;
                af[i] = ldfrag(&As[row * 64 + (sw ^ (row & 7)) * 8]);
            }
            #pragma unroll
            for (int j = 0; j < 4; ++j) {
                int row = wc * 64 + j * 16 + r16;
                bf16x8 bv = ldfrag(&Bs[row * 64 + (sw ^ (row & 7)) * 8]);
                #pragma unroll
                for (int i = 0; i < 4; ++i)
                    acc[i][j] = __builtin_amdgcn_mfma_f32_16x16x32_bf16(af[i], bv, acc[i][j], 0, 0, 0);
            }
        }
        __builtin_amdgcn_s_setprio(0);
        if (kt + 1 < NT) {
            asm volatile("s_waitcnt vmcnt(0)" ::: "memory");
            __builtin_amdgcn_sched_barrier(0);
            __builtin_amdgcn_s_barrier();
            __builtin_amdgcn_sched_barrier(0);
        }
    }
    __syncthreads();   // all waves done reading LDS before epilogue reuses it

    // ---- epilogue via LDS staging, coalesced row stores ----
    unsigned short* St = Sh;
    if (o0 == 0) {
        #pragma unroll
        for (int p = 0; p < 2; ++p) {
            if (wc == p) {
                #pragma unroll
                for (int i = 0; i < 4; ++i)
                    #pragma unroll
                    for (int j = 0; j < 4; ++j)
                        #pragma unroll
                        for (int r = 0; r < 4; ++r)
                            St[(wr * 64 + i * 16 + (lane >> 4) * 4 + r) * 72 + j * 16 + (lane & 15)] = f2bf(acc[i][j][r]);
            }
            __syncthreads();
            unsigned short* dst = p == 0 ? fT : gT;
            #pragma unroll
            for (int it = 0; it < 4; ++it) {
                int row = it * 32 + (tid >> 3);
                *(ushort8_t*)&dst[((size_t)b * N_ + n0 + row) * D_ + (tid & 7) * 8] =
                    *(ushort8_t*)&St[row * 72 + (tid & 7) * 8];
            }
            __syncthreads();
        }
    } else {
        int ho0 = o0 - 128;
        #pragma unroll
        for (int p = 0; p < 2; ++p) {
            if (wc == p) {
                #pragma unroll
                for (int i = 0; i < 4; ++i)
                    #pragma unroll
                    for (int j = 0; j < 4; ++j)
                        #pragma unroll
                        for (int r = 0; r < 4; ++r)
                            St[(j * 16 + (lane & 15)) * 136 + wr * 64 + i * 16 + (lane >> 4) * 4 + r] = f2bf(acc[i][j][r]);
            }
            __syncthreads();
            #pragma unroll
            for (int it = 0; it < 4; ++it) {
                int row = it * 16 + (tid >> 4);
                *(ushort8_t*)&hb[((size_t)b * C_ + ho0 + p * 64 + row) * N_ + n0 + (tid & 15) * 8] =
                    *(ushort8_t*)&St[row * 136 + (tid & 15) * 8];
            }
            __syncthreads();
        }
    }
}

// ---------------- stats: per column m, max/sumexp over n ----------------
__global__ __launch_bounds__(256) void k_stats(const unsigned short* __restrict__ fT,
                                               const unsigned short* __restrict__ gT,
                                               float* __restrict__ colmax,
                                               float* __restrict__ colsinv) {
    int b = blockIdx.y, m0 = blockIdx.x * 16;
    int tid = threadIdx.x, lane = tid & 63, w = tid >> 6;
    int mcol = m0 + (lane & 15);
    const unsigned short* gbase = gT + ((size_t)b * N_ + mcol) * D_ + (lane >> 4) * 8;
    bf16x8 g0 = ldfrag(gbase);
    bf16x8 g1 = ldfrag(gbase + 32);

    float mx = -1e30f, sm = 0.f;
    for (int nt = w * 32; nt < w * 32 + 32; ++nt) {
        const unsigned short* abase = fT + ((size_t)b * N_ + nt * 16 + (lane & 15)) * D_ + (lane >> 4) * 8;
        f32x4 s = {0.f, 0.f, 0.f, 0.f};
        s = __builtin_amdgcn_mfma_f32_16x16x32_bf16(ldfrag(abase), g0, s, 0, 0, 0);
        s = __builtin_amdgcn_mfma_f32_16x16x32_bf16(ldfrag(abase + 32), g1, s, 0, 0, 0);
        float tm = fmaxf(fmaxf(s[0], s[1]), fmaxf(s[2], s[3]));
        float nm = fmaxf(mx, tm);
        float c = fastexp(mx - nm);
        sm = sm * c + fastexp(s[0] - nm) + fastexp(s[1] - nm) + fastexp(s[2] - nm) + fastexp(s[3] - nm);
        mx = nm;
    }
    #pragma unroll
    for (int off = 16; off < 64; off <<= 1) {
        float omx = __shfl_xor(mx, off, 64);
        float osm = __shfl_xor(sm, off, 64);
        float nm = fmaxf(mx, omx);
        sm = sm * fastexp(mx - nm) + osm * fastexp(omx - nm);
        mx = nm;
    }
    __shared__ float lmx[4][16], lsm[4][16];
    if ((lane >> 4) == 0) { lmx[w][lane & 15] = mx; lsm[w][lane & 15] = sm; }
    __syncthreads();
    if (tid < 16) {
        float M = lmx[0][tid], S = lsm[0][tid];
        #pragma unroll
        for (int q = 1; q < 4; ++q) {
            float om = lmx[q][tid], os = lsm[q][tid];
            float nm = fmaxf(M, om);
            S = S * fastexp(M - nm) + os * fastexp(om - nm);
            M = nm;
        }
        colmax[(size_t)b * N_ + m0 + tid] = M;
        colsinv[(size_t)b * N_ + m0 + tid] = 1.0f / S;
    }
}

// ---------------- beta: betaT[b][m][n] = exp(S[n,m]-max[m]) * inv_sum[m] ----------------
__global__ __launch_bounds__(256) void k_beta(const unsigned short* __restrict__ fT,
                                              const unsigned short* __restrict__ gT,
                                              const float* __restrict__ colmax,
                                              const float* __restrict__ colsinv,
                                              unsigned short* __restrict__ betaT) {
    int b = blockIdx.z, n0 = blockIdx.y * 64, m0 = blockIdx.x * 64;
    int tid = threadIdx.x, lane = tid & 63, w = tid >> 6;
    __shared__ __align__(16) unsigned short St[64 * 72];
    const unsigned short* abase = fT + ((size_t)b * N_ + n0 + w * 16 + (lane & 15)) * D_ + (lane >> 4) * 8;
    bf16x8 a0 = ldfrag(abase);
    bf16x8 a1 = ldfrag(abase + 32);
    const int SP = 72;
    f32x4 zero = {0.f, 0.f, 0.f, 0.f};
    #pragma unroll
    for (int j = 0; j < 4; ++j) {
        int m = m0 + j * 16 + (lane & 15);
        const unsigned short* gbase = gT + ((size_t)b * N_ + m) * D_ + (lane >> 4) * 8;
        f32x4 s = zero;
        s = __builtin_amdgcn_mfma_f32_16x16x32_bf16(a0, ldfrag(gbase), s, 0, 0, 0);
        s = __builtin_amdgcn_mfma_f32_16x16x32_bf16(a1, ldfrag(gbase + 32), s, 0, 0, 0);
        float mxv = colmax[(size_t)b * N_ + m];
        float siv = colsinv[(size_t)b * N_ + m];
        #pragma unroll
        for (int r = 0; r < 4; ++r)
            St[(j * 16 + (lane & 15)) * SP + w * 16 + (lane >> 4) * 4 + r] = f2bf(fastexp(s[r] - mxv) * siv);
    }
    __syncthreads();
    int rr = tid >> 3, cp = (tid & 7) * 8;
    #pragma unroll
    for (int it = 0; it < 2; ++it) {
        int m = rr + it * 32;
        *(ushort8_t*)&betaT[((size_t)b * N_ + m0 + m) * N_ + n0 + cp] = *(ushort8_t*)&St[m * SP + cp];
    }
}

// ---------------- pv (pipelined): out[b][c][m] = gamma * sum_n betaT[m][n]*h[c][n] + x ----------------
// BM=64 (m), BC=128 (c), BK=64, double-buffered (48 KB -> 3 blocks/CU).
// STAGE(kt+1) issued BEFORE compute(kt); one vmcnt(0)+barrier per tile.
__global__ __launch_bounds__(256) void k_pv(const unsigned short* __restrict__ betaT,
                                            const unsigned short* __restrict__ hb,
                                            const float* __restrict__ x,
                                            const float* __restrict__ gamma,
                                            float* __restrict__ out) {
    const int NT = N_ / 64;
    int b = blockIdx.z, m0 = blockIdx.x * 64, c0 = blockIdx.y * 128;
    int tid = threadIdx.x, lane = tid & 63, w = tid >> 6;
    int wm = w >> 1, wc = w & 1;
    __shared__ __align__(16) unsigned short As[2][4096];    // [64 m][64 n] swz, 8 KB each
    __shared__ __align__(16) unsigned short Bs[2][8192];    // [128 c][64 n] swz, 16 KB each
    f32x4 zero = {0.f, 0.f, 0.f, 0.f};
    f32x4 acc[2][4];
    #pragma unroll
    for (int i = 0; i < 2; ++i)
        #pragma unroll
        for (int j = 0; j < 4; ++j) acc[i][j] = zero;
    int srow = lane >> 3;
    int scb = ((lane & 7) ^ srow) * 8;

    auto STAGE = [&](int kt, int p) {
        #pragma unroll
        for (int q = 0; q < 2; ++q) {
            int chunk = w * 2 + q;
            int row = chunk * 8 + srow;
            gload_lds16(betaT + ((size_t)b * N_ + m0 + row) * N_ + kt * 64 + scb, &As[p][chunk * 512]);
        }
        #pragma unroll
        for (int q = 0; q < 4; ++q) {
            int chunk = w * 4 + q;
            int row = chunk * 8 + srow;
            gload_lds16(hb + ((size_t)b * C_ + c0 + row) * N_ + kt * 64 + scb, &Bs[p][chunk * 512]);
        }
    };

    STAGE(0, 0);
    asm volatile("s_waitcnt vmcnt(0)" ::: "memory");
    __builtin_amdgcn_sched_barrier(0);
    __builtin_amdgcn_s_barrier();
    __builtin_amdgcn_sched_barrier(0);

    #pragma unroll 1
    for (int kt = 0; kt < NT; ++kt) {
        int p = kt & 1;
        if (kt + 1 < NT) STAGE(kt + 1, p ^ 1);
        __builtin_amdgcn_sched_barrier(0);
        __builtin_amdgcn_s_setprio(1);
        #pragma unroll
        for (int kk = 0; kk < 2; ++kk) {
            int colg = kk * 32 + (lane >> 4) * 8;
            bf16x8 af[2];
            #pragma unroll
            for (int i = 0; i < 2; ++i) {
                int ar = wm * 32 + i * 16 + (lane & 15);
                af[i] = ldfrag(&As[p][ar * 64 + (colg ^ ((ar & 7) << 3))]);
            }
            #pragma unroll
            for (int j = 0; j < 4; ++j) {
                int br = wc * 64 + j * 16 + (lane & 15);
                bf16x8 bv = ldfrag(&Bs[p][br * 64 + (colg ^ ((br & 7) << 3))]);
                #pragma unroll
                for (int i = 0; i < 2; ++i)
                    acc[i][j] = __builtin_amdgcn_mfma_f32_16x16x32_bf16(af[i], bv, acc[i][j], 0, 0, 0);
            }
        }
        __builtin_amdgcn_s_setprio(0);
        if (kt + 1 < NT) {
            asm volatile("s_waitcnt vmcnt(0)" ::: "memory");
            __builtin_amdgcn_sched_barrier(0);
            __builtin_amdgcn_s_barrier();
            __builtin_amdgcn_sched_barrier(0);
        }
    }

    float gv = gamma[0];
    #pragma unroll
    for (int i = 0; i < 2; ++i) {
        int mb = m0 + wm * 32 + i * 16 + (lane >> 4) * 4;
        #pragma unroll
        for (int j = 0; j < 4; ++j) {
            int c = c0 + wc * 64 + j * 16 + (lane & 15);
            size_t base = ((size_t)b * C_ + c) * N_ + mb;
            float4 xv = *(const float4*)(x + base);
            float4 ov;
            ov.x = gv * acc[i][j][0] + xv.x;
            ov.y = gv * acc[i][j][1] + xv.y;
            ov.z = gv * acc[i][j][2] + xv.z;
            ov.w = gv * acc[i][j][3] + xv.w;
            *(float4*)(out + base) = ov;
        }
    }
}

extern "C" void kernel_launch(void* const* d_in, const int* in_sizes, int n_in,
                              void* d_out, int out_size, void* d_ws, size_t ws_size,
                              hipStream_t stream) {
    const float* x     = (const float*)d_in[0];
    const float* Wq    = (const float*)d_in[1];
    const float* Wk    = (const float*)d_in[2];
    const float* Wv    = (const float*)d_in[3];
    const float* uq    = (const float*)d_in[4];
    const float* uk    = (const float*)d_in[5];
    const float* uv    = (const float*)d_in[6];
    const float* gamma = (const float*)d_in[7];
    float* out = (float*)d_out;

    char* wsb = (char*)d_ws;
    float* scales         = (float*)wsb;
    unsigned short* xT    = (unsigned short*)(wsb + 256);
    unsigned short* fT    = xT + (size_t)B_ * N_ * C_;
    unsigned short* gT    = fT + (size_t)B_ * N_ * D_;
    unsigned short* hb    = gT + (size_t)B_ * N_ * D_;
    unsigned short* betaT = hb + (size_t)B_ * C_ * N_;
    float* colmax         = (float*)(betaT + (size_t)B_ * N_ * N_);
    float* colsinv        = colmax + (size_t)B_ * N_;
    float* tpart          = colsinv + (size_t)B_ * N_;
    float* tvec           = tpart + 3 * 4 * 512;
    float* t2             = tvec + 3 * 512;
    float* wpart          = t2 + 16;
    unsigned short* Wb    = (unsigned short*)(wpart + 3 * 128);

    k_colvec<<<dim3(4, 3), 512, 0, stream>>>(Wq, Wk, Wv, uq, uk, uv, tpart);
    k_trow<<<3, 512, 0, stream>>>(tpart, tvec, t2);
    k_rowvec<<<dim3(128, 3), 256, 0, stream>>>(Wq, Wk, Wv, tvec, wpart);
    k_scale<<<3, 128, 0, stream>>>(wpart, t2, scales);
    k_wconv<<<O_ * C_ / (256 * 8), 256, 0, stream>>>(Wq, Wk, Wv, scales, Wb);
    k_transpose<<<dim3(N_ / 32, C_ / 64, B_), dim3(32, 8), 0, stream>>>(x, xT);
    k_proj<<<dim3(O_ / 128, N_ / 128, B_), 256, 0, stream>>>(xT, Wb, fT, gT, hb);
    k_stats<<<dim3(N_ / 16, B_), 256, 0, stream>>>(fT, gT, colmax, colsinv);
    k_beta<<<dim3(N_ / 64, N_ / 64, B_), 256, 0, stream>>>(fT, gT, colmax, colsinv, betaT);
    k_pv<<<dim3(N_ / 64, C_ / 128, B_), 256, 0, stream>>>(betaT, hb, x, gamma, out);
}

// Round 11
// 173.513 us; speedup vs baseline: 1.2164x; 1.2164x over previous
//
#include <hip/hip_runtime.h>
#include <hip/hip_bf16.h>
#include <math.h>

#define B_ 8
#define C_ 512
#define N_ 2048
#define D_ 64
#define O_ 640   // 64 + 64 + 512

typedef __bf16 bf16x8 __attribute__((ext_vector_type(8)));
typedef float f32x4 __attribute__((ext_vector_type(4)));
typedef unsigned short ushort8_t __attribute__((ext_vector_type(8)));
typedef unsigned short ushort4_t __attribute__((ext_vector_type(4)));

__device__ __forceinline__ unsigned short f2bf(float f) {
    unsigned int u = __builtin_bit_cast(unsigned int, f);
    u += 0x7fffu + ((u >> 16) & 1u);
    return (unsigned short)(u >> 16);
}

__device__ __forceinline__ unsigned short f2bf_hw(float f) {
    __bf16 h = (__bf16)f;
    return __builtin_bit_cast(unsigned short, h);
}

__device__ __forceinline__ float fastexp(float x) {
    return exp2f(x * 1.44269504088896340736f);
}

union FragU { ushort8_t u; bf16x8 b; };

__device__ __forceinline__ bf16x8 ldfrag(const unsigned short* p) {
    FragU t; t.u = *(const ushort8_t*)p; return t.b;
}

__device__ __forceinline__ void gload_lds16(const unsigned short* g, unsigned short* l) {
    __builtin_amdgcn_global_load_lds((const __attribute__((address_space(1))) void*)g,
                                     (__attribute__((address_space(3))) void*)l,
                                     16, 0, 0);
}

// ================= sigma chain: scale[which] = ||t|| / ||W t||, t = W^T u =================
__global__ __launch_bounds__(512) void k_colvec(const float* __restrict__ Wq,
                                                const float* __restrict__ Wk,
                                                const float* __restrict__ Wv,
                                                const float* __restrict__ uq,
                                                const float* __restrict__ uk,
                                                const float* __restrict__ uv,
                                                float* __restrict__ tpart) {
    int which = blockIdx.y, oq = blockIdx.x;
    const float* W; const float* u; int R;
    if (which == 0)      { W = Wq; u = uq; R = 64;  }
    else if (which == 1) { W = Wk; u = uk; R = 64;  }
    else                 { W = Wv; u = uv; R = 512; }
    int chunk = R >> 2;
    int i = threadIdx.x;
    float s = 0.f;
    int o0 = oq * chunk, o1 = o0 + chunk;
    for (int o = o0; o < o1; ++o) s += W[(size_t)o * 512 + i] * u[o];
    tpart[((which << 2) + oq) * 512 + i] = s;
}

__global__ __launch_bounds__(512) void k_trow(const float* __restrict__ tpart,
                                              float* __restrict__ tvec,
                                              float* __restrict__ t2) {
    int which = blockIdx.x, i = threadIdx.x;
    const float* tp = tpart + (which << 2) * 512;
    float s = tp[i] + tp[512 + i] + tp[1024 + i] + tp[1536 + i];
    tvec[which * 512 + i] = s;
    __shared__ float red[512];
    red[i] = s * s; __syncthreads();
    for (int st = 256; st > 0; st >>= 1) { if (i < st) red[i] += red[i + st]; __syncthreads(); }
    if (i == 0) t2[which] = red[0];
}

__global__ __launch_bounds__(256) void k_rowvec(const float* __restrict__ Wq,
                                                const float* __restrict__ Wk,
                                                const float* __restrict__ Wv,
                                                const float* __restrict__ tvec,
                                                float* __restrict__ wpart) {
    int which = blockIdx.y;
    const float* W; int R;
    if (which == 0)      { W = Wq; R = 64;  }
    else if (which == 1) { W = Wk; R = 64;  }
    else                 { W = Wv; R = 512; }
    int tid = threadIdx.x, lane = tid & 63, wv = tid >> 6;
    int row = blockIdx.x * 4 + wv;
    float ps = 0.f;
    if (row < R) {
        const float4* wr_ = (const float4*)(W + (size_t)row * 512);
        const float4* tv = (const float4*)(tvec + which * 512);
        float4 a0 = wr_[lane * 2], a1 = wr_[lane * 2 + 1];
        float4 b0 = tv[lane * 2], b1 = tv[lane * 2 + 1];
        float s = a0.x * b0.x + a0.y * b0.y + a0.z * b0.z + a0.w * b0.w
                + a1.x * b1.x + a1.y * b1.y + a1.z * b1.z + a1.w * b1.w;
        #pragma unroll
        for (int off = 1; off < 64; off <<= 1) s += __shfl_xor(s, off, 64);
        ps = s * s;
    }
    __shared__ float red[4];
    if (lane == 0) red[wv] = ps;
    __syncthreads();
    if (tid == 0) wpart[which * 128 + blockIdx.x] = red[0] + red[1] + red[2] + red[3];
}

__global__ __launch_bounds__(128) void k_scale(const float* __restrict__ wpart,
                                               const float* __restrict__ t2,
                                               float* __restrict__ scales) {
    int which = blockIdx.x, tid = threadIdx.x;
    float s = wpart[which * 128 + tid];
    #pragma unroll
    for (int off = 1; off < 64; off <<= 1) s += __shfl_xor(s, off, 64);
    __shared__ float r2[2];
    if ((tid & 63) == 0) r2[tid >> 6] = s;
    __syncthreads();
    if (tid == 0) scales[which] = sqrtf(t2[which] / fmaxf(r2[0] + r2[1], 1e-24f));
}

// ---------------- wconv: Wb[o][i] = bf16(W[o][i] * scale) ----------------
__global__ __launch_bounds__(256) void k_wconv(const float* __restrict__ Wq,
                                               const float* __restrict__ Wk,
                                               const float* __restrict__ Wv,
                                               const float* __restrict__ scales,
                                               unsigned short* __restrict__ Wb) {
    int gid = blockIdx.x * 256 + threadIdx.x;
    int e0 = gid * 8;
    int o = e0 >> 9, i = e0 & 511;
    const float* src; float sc;
    if (o < 64)       { src = Wq + (size_t)o * 512;         sc = scales[0]; }
    else if (o < 128) { src = Wk + (size_t)(o - 64) * 512;  sc = scales[1]; }
    else              { src = Wv + (size_t)(o - 128) * 512; sc = scales[2]; }
    float4 v0 = *(const float4*)(src + i), v1 = *(const float4*)(src + i + 4);
    ushort8_t u;
    u[0] = f2bf(v0.x * sc); u[1] = f2bf(v0.y * sc); u[2] = f2bf(v0.z * sc); u[3] = f2bf(v0.w * sc);
    u[4] = f2bf(v1.x * sc); u[5] = f2bf(v1.y * sc); u[6] = f2bf(v1.z * sc); u[7] = f2bf(v1.w * sc);
    *(ushort8_t*)&Wb[(size_t)o * 512 + i] = u;
}

// ---------------- transpose: x [B,C,N] f32 -> xT [B,N,C] bf16 ----------------
__global__ __launch_bounds__(256) void k_transpose(const float* __restrict__ x,
                                                   unsigned short* __restrict__ xT) {
    __shared__ float tile[64][33];   // [c][n]
    int b = blockIdx.z;
    int n0 = blockIdx.x * 32, c0 = blockIdx.y * 64;
    int tx = threadIdx.x, ty = threadIdx.y;  // tx: 0..31 (n), ty: 0..7
    #pragma unroll
    for (int k = 0; k < 8; ++k) {
        int c = ty + k * 8;
        tile[c][tx] = x[((size_t)b * C_ + c0 + c) * N_ + n0 + tx];
    }
    __syncthreads();
    #pragma unroll
    for (int k = 0; k < 4; ++k) {
        int n = ty + k * 8;
        unsigned int p = (unsigned int)f2bf(tile[tx * 2][n]) |
                         ((unsigned int)f2bf(tile[tx * 2 + 1][n]) << 16);
        *(unsigned int*)&xT[((size_t)b * N_ + n0 + n) * C_ + c0 + tx * 2] = p;
    }
}

// ---------------- proj: D[n,o] = sum_i xT[n,i] * Wb[o,i]; 128x128 tile, BK=64 ----------------
__global__ __launch_bounds__(256) void k_proj(const unsigned short* __restrict__ xT,
                                              const unsigned short* __restrict__ Wb,
                                              unsigned short* __restrict__ fT,
                                              unsigned short* __restrict__ gT,
                                              unsigned short* __restrict__ hb) {
    int b = blockIdx.z, n0 = blockIdx.y * 128, o0 = blockIdx.x * 128;
    int tid = threadIdx.x, lane = tid & 63, w = tid >> 6;
    int wr = w >> 1, wc = w & 1;
    __shared__ __align__(16) unsigned short Sh[16384];   // 32 KB
    unsigned short* As = Sh;          // [128 n][64 k] swizzled
    unsigned short* Bs = Sh + 8192;   // [128 o][64 k] swizzled
    f32x4 zero = {0.f, 0.f, 0.f, 0.f};
    f32x4 acc[4][4];
    #pragma unroll
    for (int i = 0; i < 4; ++i)
        #pragma unroll
        for (int j = 0; j < 4; ++j) acc[i][j] = zero;
    int r8 = lane >> 3, s = lane & 7;
    int scol = (s ^ r8) * 8;   // pre-swizzled source column (elements)

    for (int kt = 0; kt < 8; ++kt) {
        #pragma unroll
        for (int q = 0; q < 4; ++q) {
            int chunk = w * 4 + q;
            int row = chunk * 8 + r8;
            gload_lds16(xT + ((size_t)b * N_ + n0 + row) * C_ + kt * 64 + scol, &As[chunk * 512]);
            gload_lds16(Wb + (size_t)(o0 + row) * C_ + kt * 64 + scol, &Bs[chunk * 512]);
        }
        __syncthreads();
        int kg = lane >> 4, r16 = lane & 15;
        #pragma unroll
        for (int kk = 0; kk < 2; ++kk) {
            int sw = kk * 4 + kg;
            bf16x8 af[4];
            #pragma unroll
            for (int i = 0; i < 4; ++i) {
                int row = wr * 64 + i * 16 + r16;
                af[i] = ldfrag(&As[row * 64 + (sw ^ (row & 7)) * 8]);
            }
            #pragma unroll
            for (int j = 0; j < 4; ++j) {
                int row = wc * 64 + j * 16 + r16;
                bf16x8 bv = ldfrag(&Bs[row * 64 + (sw ^ (row & 7)) * 8]);
                #pragma unroll
                for (int i = 0; i < 4; ++i)
                    acc[i][j] = __builtin_amdgcn_mfma_f32_16x16x32_bf16(af[i], bv, acc[i][j], 0, 0, 0);
            }
        }
        __syncthreads();
    }

    // ---- epilogue via LDS staging, coalesced row stores ----
    unsigned short* St = Sh;
    if (o0 == 0) {
        #pragma unroll
        for (int p = 0; p < 2; ++p) {
            if (wc == p) {
                #pragma unroll
                for (int i = 0; i < 4; ++i)
                    #pragma unroll
                    for (int j = 0; j < 4; ++j)
                        #pragma unroll
                        for (int r = 0; r < 4; ++r)
                            St[(wr * 64 + i * 16 + (lane >> 4) * 4 + r) * 72 + j * 16 + (lane & 15)] = f2bf(acc[i][j][r]);
            }
            __syncthreads();
            unsigned short* dst = p == 0 ? fT : gT;
            #pragma unroll
            for (int it = 0; it < 4; ++it) {
                int row = it * 32 + (tid >> 3);
                *(ushort8_t*)&dst[((size_t)b * N_ + n0 + row) * D_ + (tid & 7) * 8] =
                    *(ushort8_t*)&St[row * 72 + (tid & 7) * 8];
            }
            __syncthreads();
        }
    } else {
        int ho0 = o0 - 128;
        #pragma unroll
        for (int p = 0; p < 2; ++p) {
            if (wc == p) {
                #pragma unroll
                for (int i = 0; i < 4; ++i)
                    #pragma unroll
                    for (int j = 0; j < 4; ++j)
                        #pragma unroll
                        for (int r = 0; r < 4; ++r)
                            St[(j * 16 + (lane & 15)) * 136 + wr * 64 + i * 16 + (lane >> 4) * 4 + r] = f2bf(acc[i][j][r]);
            }
            __syncthreads();
            #pragma unroll
            for (int it = 0; it < 4; ++it) {
                int row = it * 16 + (tid >> 4);
                *(ushort8_t*)&hb[((size_t)b * C_ + ho0 + p * 64 + row) * N_ + n0 + (tid & 15) * 8] =
                    *(ushort8_t*)&St[row * 136 + (tid & 15) * 8];
            }
            __syncthreads();
        }
    }
}

// ---------------- stats: per column m, max/sumexp over n ----------------
__global__ __launch_bounds__(256) void k_stats(const unsigned short* __restrict__ fT,
                                               const unsigned short* __restrict__ gT,
                                               float* __restrict__ colmax,
                                               float* __restrict__ colsinv) {
    int b = blockIdx.y, m0 = blockIdx.x * 16;
    int tid = threadIdx.x, lane = tid & 63, w = tid >> 6;
    int mcol = m0 + (lane & 15);
    const unsigned short* gbase = gT + ((size_t)b * N_ + mcol) * D_ + (lane >> 4) * 8;
    bf16x8 g0 = ldfrag(gbase);
    bf16x8 g1 = ldfrag(gbase + 32);

    float mx = -1e30f, sm = 0.f;
    for (int nt = w * 32; nt < w * 32 + 32; ++nt) {
        const unsigned short* abase = fT + ((size_t)b * N_ + nt * 16 + (lane & 15)) * D_ + (lane >> 4) * 8;
        f32x4 s = {0.f, 0.f, 0.f, 0.f};
        s = __builtin_amdgcn_mfma_f32_16x16x32_bf16(ldfrag(abase), g0, s, 0, 0, 0);
        s = __builtin_amdgcn_mfma_f32_16x16x32_bf16(ldfrag(abase + 32), g1, s, 0, 0, 0);
        float tm = fmaxf(fmaxf(s[0], s[1]), fmaxf(s[2], s[3]));
        float nm = fmaxf(mx, tm);
        float c = fastexp(mx - nm);
        sm = sm * c + fastexp(s[0] - nm) + fastexp(s[1] - nm) + fastexp(s[2] - nm) + fastexp(s[3] - nm);
        mx = nm;
    }
    #pragma unroll
    for (int off = 16; off < 64; off <<= 1) {
        float omx = __shfl_xor(mx, off, 64);
        float osm = __shfl_xor(sm, off, 64);
        float nm = fmaxf(mx, omx);
        sm = sm * fastexp(mx - nm) + osm * fastexp(omx - nm);
        mx = nm;
    }
    __shared__ float lmx[4][16], lsm[4][16];
    if ((lane >> 4) == 0) { lmx[w][lane & 15] = mx; lsm[w][lane & 15] = sm; }
    __syncthreads();
    if (tid < 16) {
        float M = lmx[0][tid], S = lsm[0][tid];
        #pragma unroll
        for (int q = 1; q < 4; ++q) {
            float om = lmx[q][tid], os = lsm[q][tid];
            float nm = fmaxf(M, om);
            S = S * fastexp(M - nm) + os * fastexp(om - nm);
            M = nm;
        }
        colmax[(size_t)b * N_ + m0 + tid] = M;
        colsinv[(size_t)b * N_ + m0 + tid] = 1.0f / S;
    }
}

// ---------------- fused av v3: out[b][c][m] = gamma * sum_n beta[n->m] * h[c][n] + x ----------------
// m-tile 64, c-tile 256 (beta recompute R=2), n-step 64. 512 thr / 8 waves.
// LDS 64 KB (FT dbuf 16K + HB single 32K + BS dbuf 16K) -> 2 blocks/CU; grid 512 = 2/CU.
// HB reg-staged (T14): HLOAD(kt+1) issued before PV(kt); ds_write after barrier.
__global__ __launch_bounds__(512, 4) void k_av(const unsigned short* __restrict__ fT,
                                               const unsigned short* __restrict__ gT,
                                               const unsigned short* __restrict__ hb,
                                               const float* __restrict__ colmax,
                                               const float* __restrict__ colsinv,
                                               const float* __restrict__ x,
                                               const float* __restrict__ gamma,
                                               float* __restrict__ out) {
    __shared__ __align__(16) unsigned short FT[2][4096];    // [64 n][64 d] swz, 8 KB each
    __shared__ __align__(16) unsigned short HB[16384];      // [256 c][64 n] swz, 32 KB single
    __shared__ __align__(16) unsigned short BS[2][4096];    // [64 m][64 n] swz, 8 KB each

    const int NT = N_ / 64;
    int bid = blockIdx.x;
    int xg = bid & 7, sidx = bid >> 3;       // 64 sidx values
    int mi = sidx & 31, gh = sidx >> 5;      // mi: 32 m-blocks; gh: 0..1
    int g = xg + 8 * gh;                     // 0..15 = (b, c-half) group, XCD-resident
    int b = g >> 1, ch = g & 1;
    int m0 = mi * 64, c0 = ch * 256;

    int tid = threadIdx.x, lane = tid & 63, w = tid >> 6;  // 8 waves
    int nw = w & 3, mh = w >> 2;             // nw: n-16 blk (S) / c-64 blk (PV); mh: m-32 half
    int l15 = lane & 15, lq = lane >> 4;
    int r8 = lane >> 3, sl = lane & 7;
    int scol = (sl ^ r8) * 8;                // pre-swizzled source column

    // hoisted gT B-fragments + column stats (invariant over n-loop)
    const float LOG2E = 1.44269504088896340736f;
    bf16x8 gf[2][2];
    float off_[2];
    #pragma unroll
    for (int j = 0; j < 2; ++j) {
        int m = m0 + mh * 32 + j * 16 + l15;
        #pragma unroll
        for (int kd = 0; kd < 2; ++kd)
            gf[j][kd] = ldfrag(gT + ((size_t)b * N_ + m) * D_ + kd * 32 + lq * 8);
        // beta = exp2(S*log2e - max*log2e + log2(sinv))
        off_[j] = log2f(colsinv[(size_t)b * N_ + m]) - colmax[(size_t)b * N_ + m] * LOG2E;
    }

    f32x4 zero = {0.f, 0.f, 0.f, 0.f};
    f32x4 acc[2][4];
    #pragma unroll
    for (int i = 0; i < 2; ++i)
        #pragma unroll
        for (int j = 0; j < 4; ++j) acc[i][j] = zero;

    const unsigned short* fbase = fT + ((size_t)b * N_) * D_;
    const unsigned short* hbase = hb + ((size_t)b * C_ + c0) * N_;

    ushort8_t hreg0, hreg1, hreg2, hreg3;

    // HLOAD(kt): global -> regs (256c x 64n tile; thread: 4 x 16B)
    auto HLOAD = [&](int kt) {
        const unsigned short* p0 = hbase + (size_t)((w * 4 + 0) * 8 + r8) * N_ + kt * 64 + scol;
        const unsigned short* p1 = hbase + (size_t)((w * 4 + 1) * 8 + r8) * N_ + kt * 64 + scol;
        const unsigned short* p2 = hbase + (size_t)((w * 4 + 2) * 8 + r8) * N_ + kt * 64 + scol;
        const unsigned short* p3 = hbase + (size_t)((w * 4 + 3) * 8 + r8) * N_ + kt * 64 + scol;
        hreg0 = *(const ushort8_t*)p0;
        hreg1 = *(const ushort8_t*)p1;
        hreg2 = *(const ushort8_t*)p2;
        hreg3 = *(const ushort8_t*)p3;
    };
    // HWRITE: regs -> HB (same layout gload_lds would produce: chunk*512 + lane*8)
    auto HWRITE = [&]() {
        *(ushort8_t*)&HB[(w * 4 + 0) * 512 + lane * 8] = hreg0;
        *(ushort8_t*)&HB[(w * 4 + 1) * 512 + lane * 8] = hreg1;
        *(ushort8_t*)&HB[(w * 4 + 2) * 512 + lane * 8] = hreg2;
        *(ushort8_t*)&HB[(w * 4 + 3) * 512 + lane * 8] = hreg3;
    };
    auto STAGE_FT = [&](int kt, int p) {
        gload_lds16(fbase + ((size_t)kt * 64 + w * 8 + r8) * D_ + scol, &FT[p][w * 512]);
    };
    // S + beta for one tile: reads FT[p], writes BS[p]
    auto SPHASE = [&](int p) {
        int arow = nw * 16 + l15;
        bf16x8 af0 = ldfrag(&FT[p][arow * 64 + ((lq ^ (arow & 7)) * 8)]);
        bf16x8 af1 = ldfrag(&FT[p][arow * 64 + (((4 + lq) ^ (arow & 7)) * 8)]);
        #pragma unroll
        for (int j = 0; j < 2; ++j) {
            f32x4 sv = zero;
            sv = __builtin_amdgcn_mfma_f32_16x16x32_bf16(af0, gf[j][0], sv, 0, 0, 0);
            sv = __builtin_amdgcn_mfma_f32_16x16x32_bf16(af1, gf[j][1], sv, 0, 0, 0);
            int mrel = mh * 32 + j * 16 + l15;
            ushort4_t pk;
            #pragma unroll
            for (int r = 0; r < 4; ++r)
                pk[r] = f2bf_hw(exp2f(fmaf(sv[r], LOG2E, off_[j])));
            int nt = nw * 16 + lq * 4;
            *(ushort4_t*)&BS[p][mrel * 64 + (((nt >> 3) ^ (mrel & 7)) * 8) + (nt & 7)] = pk;
        }
    };
    // PV: reads BS[p], HB
    auto PVPHASE = [&](int p) {
        __builtin_amdgcn_s_setprio(1);
        #pragma unroll
        for (int kk = 0; kk < 2; ++kk) {
            int ng = kk * 4 + lq;
            bf16x8 pa[2];
            #pragma unroll
            for (int i = 0; i < 2; ++i) {
                int mr = mh * 32 + i * 16 + l15;
                pa[i] = ldfrag(&BS[p][mr * 64 + ((ng ^ (mr & 7)) * 8)]);
            }
            #pragma unroll
            for (int j = 0; j < 4; ++j) {
                int cr = nw * 64 + j * 16 + l15;
                bf16x8 hv = ldfrag(&HB[cr * 64 + ((ng ^ (cr & 7)) * 8)]);
                #pragma unroll
                for (int i = 0; i < 2; ++i)
                    acc[i][j] = __builtin_amdgcn_mfma_f32_16x16x32_bf16(pa[i], hv, acc[i][j], 0, 0, 0);
            }
        }
        __builtin_amdgcn_s_setprio(0);
    };

    // ---- prologue ----
    STAGE_FT(0, 0);
    HLOAD(0);
    asm volatile("s_waitcnt vmcnt(0)" ::: "memory");   // FT[0] + H regs ready
    __builtin_amdgcn_sched_barrier(0);
    HWRITE();
    asm volatile("s_waitcnt lgkmcnt(0)" ::: "memory");
    __builtin_amdgcn_sched_barrier(0);
    __builtin_amdgcn_s_barrier();                      // FT[0], HB visible
    __builtin_amdgcn_sched_barrier(0);
    SPHASE(0);                                         // beta(0) -> BS[0]
    asm volatile("s_waitcnt lgkmcnt(0)" ::: "memory");
    __builtin_amdgcn_sched_barrier(0);
    __builtin_amdgcn_s_barrier();                      // BS[0] visible
    __builtin_amdgcn_sched_barrier(0);

    #pragma unroll 1
    for (int kt = 0; kt < NT; ++kt) {
        int p = kt & 1;
        if (kt + 1 < NT) {
            HLOAD(kt + 1);                             // global->regs, hides under PV
            STAGE_FT(kt + 1, p ^ 1);
            __builtin_amdgcn_sched_barrier(0);
        }
        PVPHASE(p);
        if (kt + 1 < NT) {
            asm volatile("s_waitcnt vmcnt(0)" ::: "memory");  // H regs + FT landed
            __builtin_amdgcn_sched_barrier(0);
            __builtin_amdgcn_s_barrier();              // all waves done PV (HB, BS[p] free)
            __builtin_amdgcn_sched_barrier(0);
            HWRITE();                                  // HB <- tile kt+1
            SPHASE(p ^ 1);                             // beta(kt+1) -> BS[p^1] (reads FT[p^1])
            asm volatile("s_waitcnt lgkmcnt(0)" ::: "memory");
            __builtin_amdgcn_sched_barrier(0);
            __builtin_amdgcn_s_barrier();              // HB + BS[p^1] visible
            __builtin_amdgcn_sched_barrier(0);
        }
    }

    float gv = gamma[0];
    #pragma unroll
    for (int i = 0; i < 2; ++i) {
        int mabs = m0 + mh * 32 + i * 16 + lq * 4;
        #pragma unroll
        for (int j = 0; j < 4; ++j) {
            int cabs = c0 + nw * 64 + j * 16 + l15;
            size_t base = ((size_t)b * C_ + cabs) * N_ + mabs;
            float4 xv = *(const float4*)(x + base);
            float4 ov;
            ov.x = gv * acc[i][j][0] + xv.x;
            ov.y = gv * acc[i][j][1] + xv.y;
            ov.z = gv * acc[i][j][2] + xv.z;
            ov.w = gv * acc[i][j][3] + xv.w;
            *(float4*)(out + base) = ov;
        }
    }
}

extern "C" void kernel_launch(void* const* d_in, const int* in_sizes, int n_in,
                              void* d_out, int out_size, void* d_ws, size_t ws_size,
                              hipStream_t stream) {
    const float* x     = (const float*)d_in[0];
    const float* Wq    = (const float*)d_in[1];
    const float* Wk    = (const float*)d_in[2];
    const float* Wv    = (const float*)d_in[3];
    const float* uq    = (const float*)d_in[4];
    const float* uk    = (const float*)d_in[5];
    const float* uv    = (const float*)d_in[6];
    const float* gamma = (const float*)d_in[7];
    float* out = (float*)d_out;

    char* wsb = (char*)d_ws;
    float* scales         = (float*)wsb;
    unsigned short* xT    = (unsigned short*)(wsb + 256);
    unsigned short* fT    = xT + (size_t)B_ * N_ * C_;
    unsigned short* gT    = fT + (size_t)B_ * N_ * D_;
    unsigned short* hb    = gT + (size_t)B_ * N_ * D_;
    float* colmax         = (float*)(hb + (size_t)B_ * C_ * N_);
    float* colsinv        = colmax + (size_t)B_ * N_;
    float* tpart          = colsinv + (size_t)B_ * N_;
    float* tvec           = tpart + 3 * 4 * 512;
    float* t2             = tvec + 3 * 512;
    float* wpart          = t2 + 16;
    unsigned short* Wb    = (unsigned short*)(wpart + 3 * 128);

    k_colvec<<<dim3(4, 3), 512, 0, stream>>>(Wq, Wk, Wv, uq, uk, uv, tpart);
    k_trow<<<3, 512, 0, stream>>>(tpart, tvec, t2);
    k_rowvec<<<dim3(128, 3), 256, 0, stream>>>(Wq, Wk, Wv, tvec, wpart);
    k_scale<<<3, 128, 0, stream>>>(wpart, t2, scales);
    k_wconv<<<O_ * C_ / (256 * 8), 256, 0, stream>>>(Wq, Wk, Wv, scales, Wb);
    k_transpose<<<dim3(N_ / 32, C_ / 64, B_), dim3(32, 8), 0, stream>>>(x, xT);
    k_proj<<<dim3(O_ / 128, N_ / 128, B_), 256, 0, stream>>>(xT, Wb, fT, gT, hb);
    k_stats<<<dim3(N_ / 16, B_), 256, 0, stream>>>(fT, gT, colmax, colsinv);
    k_av<<<512, 512, 0, stream>>>(fT, gT, hb, colmax, colsinv, x, gamma, out);
}